// Round 8
// baseline (127.271 us; speedup 1.0000x reference)
//
#include <hip/hip_runtime.h>
#include <cstdint>

#define TDIM 8192   // B_*S_ = 4*2048 flattened tokens
#define MDIM 1024   // in_features (GEMM K)
#define NDIM 1024   // out_features
#define KBITS 8
#define BK 64       // K-depth per A-staging tile
#define BT 128      // token-rows per block
#define BN 128      // n-cols per block
#define NTILES (MDIM / BK)   // 16

typedef __bf16 bf16x8 __attribute__((ext_vector_type(8)));
typedef float f32x4 __attribute__((ext_vector_type(4)));

#define GAS(p) ((__attribute__((address_space(1))) void*)(uintptr_t)(p))
#define LAS(p) ((__attribute__((address_space(3))) void*)(uintptr_t)(p))

__device__ __forceinline__ unsigned f2bf(float f) {
    union { float f; unsigned u; } v; v.f = f;
    unsigned r = v.u + 0x7fffu + ((v.u >> 16) & 1u);  // round-to-nearest-even
    return r >> 16;
}

// ---- prep = W-fold ONLY (x never pre-cast: gemm stages fp32 x directly) ----
// 1024 blocks: Wt[n][m] = bf16(sum_k scale[k][n]*binary[k][m][n]), 32x32 tiles,
// written in the r6/r7-VERIFIED packed fragment layout:
//   short off = ((n>>4)*128 + (m>>3))*128 + (n&15)*8 + (m&7)
__global__ __launch_bounds__(256) void wfold_kernel(const float* __restrict__ binary,
                                                    const float* __restrict__ scale,
                                                    unsigned short* __restrict__ wtrp) {
    __shared__ float tile[32][33];
    const int tid = threadIdx.x;
    const int n0 = (blockIdx.x & 31) * 32;
    const int m0 = (blockIdx.x >> 5) * 32;
    const int r = tid >> 3;          // m offset 0..31
    const int cn = (tid & 7) * 4;    // n offset 0..28 step 4
    f32x4 acc = {0.f, 0.f, 0.f, 0.f};
#pragma unroll
    for (int k = 0; k < KBITS; ++k) {
        f32x4 v = *(const f32x4*)(binary + ((size_t)k * MDIM + m0 + r) * NDIM + n0 + cn);
        f32x4 s = *(const f32x4*)(scale + (size_t)k * NDIM + n0 + cn);
        acc += v * s;
    }
#pragma unroll
    for (int e = 0; e < 4; ++e) tile[cn + e][r] = acc[e];
    __syncthreads();
    const int rn = tid >> 3;         // n offset 0..31
    const int cm = (tid & 7) * 4;    // m offset 0..28 step 4
    const int n = n0 + rn;
    const int m = m0 + cm;
    ushort4 o4;
    o4.x = (unsigned short)f2bf(tile[rn][cm + 0]);
    o4.y = (unsigned short)f2bf(tile[rn][cm + 1]);
    o4.z = (unsigned short)f2bf(tile[rn][cm + 2]);
    o4.w = (unsigned short)f2bf(tile[rn][cm + 3]);
    *(ushort4*)(wtrp + ((size_t)(n >> 4) * 128 + (m >> 3)) * 128 + (n & 15) * 8 + (m & 7)) = o4;
}

__device__ __forceinline__ bf16x8 cvt8(f32x4 lo, f32x4 hi) {
    bf16x8 r;
    r[0] = (__bf16)lo[0]; r[1] = (__bf16)lo[1]; r[2] = (__bf16)lo[2]; r[3] = (__bf16)lo[3];
    r[4] = (__bf16)hi[0]; r[5] = (__bf16)hi[1]; r[6] = (__bf16)hi[2]; r[7] = (__bf16)hi[3];
    return r;
}

// ---- gemm: out[t][n] = sum_m bf16(x[t][m])*Wt[n][m] + bias[n] ----
// A: fp32 x staged DIRECTLY via global_load_lds (DMA is dtype-agnostic) into a
//    64KB double-buffered LDS; cast fp32->bf16 on the LDS->VGPR fragment read.
//    This deletes the 48MB xb round-trip (prep x-read 32MB + xb write 16MB)
//    while KEEPING the r4-verified async staging loop (issue-early, 1 barrier).
// B: r7-verified packed-direct path (global->VGPR from 2MB L2-resident wtrp).
// fp32-A swizzle: row = 16 granules (16B); LDS slot col c holds global granule
//    g = c ^ (row&15). Fragment (h,q) granules gk=8h+2q, gk+1 read individually
//    at cols gk^ (m&15), (gk+1)^(m&15): per 16-lane phase the XOR is a bijection
//    over 16 cols -> 2 lanes/bank = free aliasing.
// grid (t=64, n=8): 64%8==0 -> linear%8 == x%8: per XCD 8 fp32 A-strips (4MB,
// ~32KB hot window) + packed B (2MB) stay L2-resident. 2 blocks/CU.
__global__ __launch_bounds__(256, 2) void gemm_kernel(const float* __restrict__ x,
                                                      const unsigned short* __restrict__ wtrp,
                                                      const float* __restrict__ bias,
                                                      float* __restrict__ out) {
    constexpr int ASZ = BT * BK;        // 8192 fp32 (32 KB) per buffer
    __shared__ __attribute__((aligned(16))) float lds[2 * ASZ];  // 64 KB

    const int tid = threadIdx.x;
    const int lane = tid & 63;
    const int wv = tid >> 6;        // 0..3
    const int wm = wv >> 1;         // 0..1 (64-row strip)
    const int wn = wv & 1;          // 0..1 (64-col strip)
    const int lrow = lane & 15;
    const int q = lane >> 4;

    const int t0 = blockIdx.x * BT;
    const int n0 = blockIdx.y * BN;
    const int nt0 = blockIdx.y * (BN / 16);   // 8 packed col-tiles per block

    // A staging map: slot s (row r = s>>4, col c = s&15) holds global granule
    // g = c ^ (r&15) of row r. 8 slots/thread covers 128 rows x 16 granules.
    const float* srcA[8];
    int dstA[8];
#pragma unroll
    for (int j = 0; j < 8; ++j) {
        int s = tid + j * 256;              // [0, 2048)
        int r = s >> 4;
        int g = (s & 15) ^ (r & 15);
        srcA[j] = x + (size_t)(t0 + r) * MDIM + g * 4;
        dstA[j] = s * 4;                    // fp32 index
    }

    // A fragment LDS offsets (fp32 indices): row m, k-half h, granules gk, gk+1
    int a_lo[2][4], a_hi[2][4];
#pragma unroll
    for (int h = 0; h < 2; ++h)
#pragma unroll
        for (int i = 0; i < 4; ++i) {
            int m = wm * 64 + i * 16 + lrow;
            int e = m & 15;
            int gk = 8 * h + 2 * q;
            a_lo[h][i] = m * 64 + ((gk    ) ^ e) * 4;
            a_hi[h][i] = m * 64 + ((gk + 1) ^ e) * 4;
        }

    // B fragment base pointers (r6/r7-verified): chunk(tile, g = ks*4+q, ln = lrow)
    const unsigned short* bbase[4];
#pragma unroll
    for (int i = 0; i < 4; ++i)
        bbase[i] = wtrp + (size_t)(nt0 + wn * 4 + i) * 16384 + q * 128 + lrow * 8;

    f32x4 acc[4][4];
    const f32x4 zero = {0.f, 0.f, 0.f, 0.f};
#pragma unroll
    for (int i = 0; i < 4; ++i)
#pragma unroll
        for (int j = 0; j < 4; ++j) acc[i][j] = zero;

    auto stageA = [&](int bufsel, int t) {
        float* bb = lds + bufsel * ASZ;
        const int k0 = t * BK;
#pragma unroll
        for (int j = 0; j < 8; ++j)
            __builtin_amdgcn_global_load_lds(GAS(srcA[j] + k0), LAS(bb + dstA[j]), 16, 0, 0);
    };

    // prologue: stage A tile 0, drain, go.
    stageA(0, 0);
    __syncthreads();

#pragma unroll
    for (int t = 0; t < NTILES; ++t) {
        const int cur = t & 1;

        // B fragments for this tile (both k-halves): plain global loads, issued
        // first so their waits never drain the A prefetch below.
        bf16x8 bfr0[4], bfr1[4];
#pragma unroll
        for (int i = 0; i < 4; ++i) bfr0[i] = *(const bf16x8*)(bbase[i] + (t * 2 + 0) * 512);
#pragma unroll
        for (int i = 0; i < 4; ++i) bfr1[i] = *(const bf16x8*)(bbase[i] + (t * 2 + 1) * 512);

        // A staging for t+1: latency hides under this tile's reads + MFMAs.
        if (t + 1 < NTILES) stageA(cur ^ 1, t + 1);

        const float* base = lds + cur * ASZ;
#pragma unroll
        for (int h = 0; h < 2; ++h) {
            bf16x8 af[4];
#pragma unroll
            for (int i = 0; i < 4; ++i) {
                f32x4 lo = *(const f32x4*)(base + a_lo[h][i]);
                f32x4 hi = *(const f32x4*)(base + a_hi[h][i]);
                af[i] = cvt8(lo, hi);
            }
            __builtin_amdgcn_s_setprio(1);
#pragma unroll
            for (int i = 0; i < 4; ++i)
#pragma unroll
                for (int j = 0; j < 4; ++j)
                    acc[i][j] = __builtin_amdgcn_mfma_f32_16x16x32_bf16(
                        af[i], (h == 0) ? bfr0[j] : bfr1[j], acc[i][j], 0, 0, 0);
            __builtin_amdgcn_s_setprio(0);
        }

        if (t + 1 < NTILES) __syncthreads();
    }

    // epilogue (verified): C/D layout col=lane&15 (n), row=q*4+reg (t). fuse bias.
#pragma unroll
    for (int j = 0; j < 4; ++j) {
        const int n = n0 + wn * 64 + j * 16 + lrow;
        const float bv = bias[n];
#pragma unroll
        for (int i = 0; i < 4; ++i) {
            const int tb = t0 + wm * 64 + i * 16 + q * 4;
#pragma unroll
            for (int r = 0; r < 4; ++r) {
                out[(size_t)(tb + r) * NDIM + n] = acc[i][j][r] + bv;
            }
        }
    }
}

extern "C" void kernel_launch(void* const* d_in, const int* in_sizes, int n_in,
                              void* d_out, int out_size, void* d_ws, size_t ws_size,
                              hipStream_t stream) {
    const float* x      = (const float*)d_in[0];   // [4,2048,1024] fp32
    const float* binary = (const float*)d_in[1];   // [8,1024,1024] fp32 (+/-1)
    const float* scale  = (const float*)d_in[2];   // [8,1,1024] fp32
    const float* bias   = (const float*)d_in[3];   // [1024] fp32
    float* out = (float*)d_out;                    // [4,2048,1024] fp32

    unsigned short* wtrp = (unsigned short*)d_ws;  // 2 MB packed bf16 Wt

    wfold_kernel<<<1024, 256, 0, stream>>>(binary, scale, wtrp);
    gemm_kernel<<<dim3(TDIM / BT, NDIM / BN), 256, 0, stream>>>(x, wtrp, bias, out);
}

// Round 9
// 123.433 us; speedup vs baseline: 1.0311x; 1.0311x over previous
//
#include <hip/hip_runtime.h>
#include <cstdint>

#define TDIM 8192   // B_*S_ = 4*2048 flattened tokens
#define MDIM 1024   // in_features (GEMM K)
#define NDIM 1024   // out_features
#define KBITS 8
#define BK 64       // K-depth per staging tile
#define BT 128      // token-rows per block
#define BN 128      // n-cols per block
#define NTILES (MDIM / BK)   // 16

typedef __bf16 bf16x8 __attribute__((ext_vector_type(8)));
typedef float f32x4 __attribute__((ext_vector_type(4)));

#define GAS(p) ((__attribute__((address_space(1))) void*)(uintptr_t)(p))
#define LAS(p) ((__attribute__((address_space(3))) void*)(uintptr_t)(p))

__device__ __forceinline__ unsigned short f2bf(float f) {
    union { float f; unsigned u; } v; v.f = f;
    unsigned r = v.u + 0x7fffu + ((v.u >> 16) & 1u);  // round-to-nearest-even
    return (unsigned short)(r >> 16);
}

// ---- fused prep (verified; cast-in-prep beats every in-gemm cast placement:
// r2 reg-staged 44.8us, r8 fp32-LDS ~38us, this ~25+13us) ----
// blocks [0,1024): W-fold 32x32 tiles: Wt[n][m] = bf16(sum_k scale[k][n]*binary[k][m][n])
// blocks [1024,5120): x fp32 -> bf16 cast, 8 elems/thread, coalesced.
__global__ __launch_bounds__(256) void prep_kernel(const float* __restrict__ x,
                                                   unsigned short* __restrict__ xb,
                                                   const float* __restrict__ binary,
                                                   const float* __restrict__ scale,
                                                   unsigned short* __restrict__ wtr) {
    __shared__ float tile[32][33];
    const int tid = threadIdx.x;
    if (blockIdx.x >= 1024) {
        size_t idx = ((size_t)(blockIdx.x - 1024) * 256 + tid) * 8;
        float4 a = *(const float4*)(x + idx);
        float4 b = *(const float4*)(x + idx + 4);
        uint4 o;
        o.x = (unsigned)f2bf(a.x) | ((unsigned)f2bf(a.y) << 16);
        o.y = (unsigned)f2bf(a.z) | ((unsigned)f2bf(a.w) << 16);
        o.z = (unsigned)f2bf(b.x) | ((unsigned)f2bf(b.y) << 16);
        o.w = (unsigned)f2bf(b.z) | ((unsigned)f2bf(b.w) << 16);
        *(uint4*)(xb + idx) = o;
        return;
    }
    const int n0 = (blockIdx.x & 31) * 32;
    const int m0 = (blockIdx.x >> 5) * 32;
    const int r = tid >> 3;
    const int cn = (tid & 7) * 4;
    f32x4 acc = {0.f, 0.f, 0.f, 0.f};
#pragma unroll
    for (int k = 0; k < KBITS; ++k) {
        f32x4 v = *(const f32x4*)(binary + ((size_t)k * MDIM + m0 + r) * NDIM + n0 + cn);
        f32x4 s = *(const f32x4*)(scale + (size_t)k * NDIM + n0 + cn);
        acc += v * s;
    }
#pragma unroll
    for (int e = 0; e < 4; ++e) tile[cn + e][r] = acc[e];
    __syncthreads();
    const int rn = tid >> 3;
    const int cm = (tid & 7) * 4;
    ushort4 o4;
    o4.x = f2bf(tile[rn][cm + 0]);
    o4.y = f2bf(tile[rn][cm + 1]);
    o4.z = f2bf(tile[rn][cm + 2]);
    o4.w = f2bf(tile[rn][cm + 3]);
    *(ushort4*)(wtr + (size_t)(n0 + rn) * MDIM + m0 + cm) = o4;
}

// ---- gemm: out[t][n] = sum_m xb[t][m]*Wt[n][m] + bias[n] ----
// 128x128 tile, 4 waves (2Mx2N, per-wave 64x64), BK=64, double-buffered (64KB
// LDS) -> 2 blocks/CU (co-resident block covers barrier drain / prologue /
// epilogue burst). This is the empirical best of six structural variants; at
// this problem's N=1024 the 256^2 8-phase template would leave half the CUs
// idle (128 blocks), so the m97-class structure is the HIP-source ceiling here.
// grid (t=64, n=8): 64%8==0 -> linear%8 == x%8: per XCD 8 A-strips (2MB) +
// all of B (2MB) stay L2-resident.
__global__ __launch_bounds__(256, 2) void gemm_kernel(const unsigned short* __restrict__ xb,
                                                      const unsigned short* __restrict__ wtr,
                                                      const float* __restrict__ bias,
                                                      float* __restrict__ out) {
    constexpr int ASZ = BT * BK;        // 8192 elems (16 KB)
    constexpr int BSZ = BN * BK;        // 8192 elems (16 KB)
    constexpr int BUF = ASZ + BSZ;      // 16384 elems (32 KB) per buffer
    __shared__ __attribute__((aligned(16))) unsigned short lds[2 * BUF];  // 64 KB

    const int tid = threadIdx.x;
    const int lane = tid & 63;
    const int wv = tid >> 6;        // 0..3
    const int wm = wv >> 1;         // 0..1 (64-row strip)
    const int wn = wv & 1;          // 0..1 (64-col strip)
    const int lrow = lane & 15;
    const int q = lane >> 4;

    const int t0 = blockIdx.x * BT;
    const int n0 = blockIdx.y * BN;

    // staging map: granule (16B) s -> LDS slot s, holding global granule
    // (s&7)^(r&7) of row r = s>>3 (XOR swizzle; bank-conflict-free, verified).
    const unsigned short* srcA[4];
    int dstA[4];
    const unsigned short* srcB[4];
    int dstB[4];
#pragma unroll
    for (int j = 0; j < 4; ++j) {
        int s = tid + j * 256;              // [0, 1024): 128 rows x 8 granules
        int r = s >> 3;
        int g = (s & 7) ^ (r & 7);
        srcA[j] = xb + (size_t)(t0 + r) * MDIM + g * 8;
        dstA[j] = s * 8;
        srcB[j] = wtr + (size_t)(n0 + r) * MDIM + g * 8;
        dstB[j] = ASZ + s * 8;
    }

    // fragment LDS offsets: row m, k-half h, granule (h*4+q)^(m&7)
    int a_off[2][4], b_off[2][4];
#pragma unroll
    for (int h = 0; h < 2; ++h)
#pragma unroll
        for (int i = 0; i < 4; ++i) {
            int m = wm * 64 + i * 16 + lrow;
            a_off[h][i] = (m * 8 + ((h * 4 + q) ^ (m & 7))) * 8;
            int n = wn * 64 + i * 16 + lrow;
            b_off[h][i] = ASZ + (n * 8 + ((h * 4 + q) ^ (n & 7))) * 8;
        }

    f32x4 acc[4][4];
    const f32x4 zero = {0.f, 0.f, 0.f, 0.f};
#pragma unroll
    for (int i = 0; i < 4; ++i)
#pragma unroll
        for (int j = 0; j < 4; ++j) acc[i][j] = zero;

    auto stage = [&](int bufsel, int t) {
        unsigned short* bb = lds + bufsel * BUF;
        const int k0 = t * BK;
#pragma unroll
        for (int j = 0; j < 4; ++j)
            __builtin_amdgcn_global_load_lds(GAS(srcA[j] + k0), LAS(bb + dstA[j]), 16, 0, 0);
#pragma unroll
        for (int j = 0; j < 4; ++j)
            __builtin_amdgcn_global_load_lds(GAS(srcB[j] + k0), LAS(bb + dstB[j]), 16, 0, 0);
    };

    // prologue: stage tile 0, drain, go.
    stage(0, 0);
    __syncthreads();

#pragma unroll
    for (int t = 0; t < NTILES; ++t) {
        const int cur = t & 1;
        // issue tile t+1's staging first: its HBM/L2 latency hides under this
        // tile's ds_reads + MFMAs; the boundary __syncthreads then drains it.
        if (t + 1 < NTILES) stage(cur ^ 1, t + 1);

        const unsigned short* base = lds + cur * BUF;
#pragma unroll
        for (int h = 0; h < 2; ++h) {
            bf16x8 af[4], bfr[4];
#pragma unroll
            for (int i = 0; i < 4; ++i) af[i] = *(const bf16x8*)(base + a_off[h][i]);
#pragma unroll
            for (int i = 0; i < 4; ++i) bfr[i] = *(const bf16x8*)(base + b_off[h][i]);
            __builtin_amdgcn_s_setprio(1);
#pragma unroll
            for (int i = 0; i < 4; ++i)
#pragma unroll
                for (int j = 0; j < 4; ++j)
                    acc[i][j] = __builtin_amdgcn_mfma_f32_16x16x32_bf16(af[i], bfr[j],
                                                                        acc[i][j], 0, 0, 0);
            __builtin_amdgcn_s_setprio(0);
        }

        if (t + 1 < NTILES) __syncthreads();
    }

    // epilogue: C/D layout col=lane&15 (n), row=q*4+reg (t). fuse bias.
#pragma unroll
    for (int j = 0; j < 4; ++j) {
        const int n = n0 + wn * 64 + j * 16 + lrow;
        const float bv = bias[n];
#pragma unroll
        for (int i = 0; i < 4; ++i) {
            const int tb = t0 + wm * 64 + i * 16 + q * 4;
#pragma unroll
            for (int r = 0; r < 4; ++r) {
                out[(size_t)(tb + r) * NDIM + n] = acc[i][j][r] + bv;
            }
        }
    }
}

extern "C" void kernel_launch(void* const* d_in, const int* in_sizes, int n_in,
                              void* d_out, int out_size, void* d_ws, size_t ws_size,
                              hipStream_t stream) {
    const float* x      = (const float*)d_in[0];   // [4,2048,1024] fp32
    const float* binary = (const float*)d_in[1];   // [8,1024,1024] fp32 (+/-1)
    const float* scale  = (const float*)d_in[2];   // [8,1,1024] fp32
    const float* bias   = (const float*)d_in[3];   // [1024] fp32
    float* out = (float*)d_out;                    // [4,2048,1024] fp32

    unsigned short* xb  = (unsigned short*)d_ws;            // 16 MB bf16 x
    unsigned short* wtr = xb + (size_t)TDIM * MDIM;         // 2 MB bf16 Wt[n][m]

    prep_kernel<<<1024 + 4096, 256, 0, stream>>>(x, xb, binary, scale, wtr);
    gemm_kernel<<<dim3(TDIM / BT, NDIM / BN), 256, 0, stream>>>(xb, wtr, bias, out);
}